// Round 4
// baseline (252.398 us; speedup 1.0000x reference)
//
#include <hip/hip_runtime.h>

#define C_  8
#define NQ_ 16
#define NK_ 32
#define B_  128
#define D_  128
#define E_  512
#define H_  8
#define A_  64
#define O_  64

typedef __attribute__((ext_vector_type(4))) float f32x4;
typedef __attribute__((ext_vector_type(8))) short bf16x8;
typedef __attribute__((ext_vector_type(4))) short bf16x4;

__device__ __forceinline__ short f2bf(float f) {
    union { float f; unsigned u; } v; v.f = f;
    unsigned r = v.u + 0x7fffu + ((v.u >> 16) & 1u);
    return (short)(r >> 16);
}

// ---------------------------------------------------------------------------
// Kernel 1: fused PE + per-(c,n) QKV projections.  ROUND-0 VERBATIM (87 us).
// NOTE: needs ~104 VGPR; do NOT cap via __launch_bounds__ min-waves — both
// (256,5) and 2-deep W prefetch spilled the 64-reg accumulator (r1, r2).
// ---------------------------------------------------------------------------
__global__ __launch_bounds__(256) void qkv_proj_kernel(
    const float* __restrict__ qin, const float* __restrict__ kin,
    const float* __restrict__ Wq, const float* __restrict__ Wk,
    const float* __restrict__ Wv,
    short* __restrict__ wsq, short* __restrict__ wsk, short* __restrict__ wsv)
{
    __shared__ __align__(16) short Alds[B_][72];   // [row b][k], pad 64->72
    __shared__ __align__(16) short Blds[128][72];  // [e][k] (transposed W)
    __shared__ float pe_buf[D_];

    const int tid   = threadIdx.x;
    const int blk   = blockIdx.x;
    const int e_blk = blk & 3;
    const int unit  = blk >> 2;

    const float* X; const float* W; short* Y; int n; size_t ypitch;
    if (unit < C_ * NQ_) {
        const int c = unit >> 4;
        n = unit & 15;
        X = qin + (size_t)unit * B_ * D_;
        W = Wq  + (size_t)unit * D_ * E_;
        Y = wsq + (size_t)c * B_ * NQ_ * E_ + (size_t)n * E_;
        ypitch = (size_t)NQ_ * E_;
    } else if (unit < C_ * (NQ_ + NK_)) {
        const int u = unit - C_ * NQ_;
        const int c = u >> 5;
        n = u & 31;
        X = kin + (size_t)u * B_ * D_;
        W = Wk  + (size_t)u * D_ * E_;
        Y = wsk + (size_t)c * B_ * NK_ * E_ + (size_t)n * E_;
        ypitch = (size_t)NK_ * E_;
    } else {
        const int u = unit - C_ * (NQ_ + NK_);
        const int c = u >> 5;
        n = u & 31;
        X = kin + (size_t)u * B_ * D_;
        W = Wv  + (size_t)u * D_ * E_;
        Y = wsv + (size_t)c * B_ * NK_ * E_ + (size_t)n * E_;
        ypitch = (size_t)NK_ * E_;
    }

    if (tid < D_) {
        const int d = tid;
        const float freq = expf((float)(d & ~1) * (-9.210340371976184f / (float)D_));
        const float arg  = (float)n * freq;
        pe_buf[d] = (d & 1) ? cosf(arg) : sinf(arg);
    }
    __syncthreads();

    const int wv   = tid >> 6;
    const int lane = tid & 63;
    const int lr   = lane & 15;
    const int quad = lane >> 4;
    const int wrow = (wv >> 1) * 64;
    const int wcol = (wv & 1) * 64;

    f32x4 acc[4][4];
    for (int m = 0; m < 4; ++m)
        for (int nf = 0; nf < 4; ++nf)
            acc[m][nf] = (f32x4){0.f, 0.f, 0.f, 0.f};

    const int e  = tid & 127;
    const int kg = (tid >> 7) * 32;

    for (int k0 = 0; k0 < D_; k0 += 64) {
        f32x4 a_raw[8];
        #pragma unroll
        for (int i = 0; i < 8; ++i) {
            const int id  = tid + 256 * i;
            const int row = id >> 4;
            const int ch  = id & 15;
            a_raw[i] = *(const f32x4*)(X + (size_t)row * D_ + k0 + ch * 4);
        }
        float b_raw[32];
        const float* bsrc = W + (size_t)(k0 + kg) * E_ + e_blk * 128 + e;
        #pragma unroll
        for (int i = 0; i < 32; ++i)
            b_raw[i] = bsrc[(size_t)i * E_];

        #pragma unroll
        for (int i = 0; i < 8; ++i) {
            const int id  = tid + 256 * i;
            const int row = id >> 4;
            const int ch  = id & 15;
            bf16x4 v;
            #pragma unroll
            for (int j = 0; j < 4; ++j)
                v[j] = f2bf(a_raw[i][j] + pe_buf[k0 + ch * 4 + j]);
            *(bf16x4*)&Alds[row][ch * 4] = v;
        }
        #pragma unroll
        for (int i = 0; i < 4; ++i) {
            bf16x8 v;
            #pragma unroll
            for (int j = 0; j < 8; ++j)
                v[j] = f2bf(b_raw[i * 8 + j]);
            *(bf16x8*)&Blds[e][kg + i * 8] = v;
        }
        __syncthreads();

        for (int ks = 0; ks < 2; ++ks) {
            const int kc = ks * 32 + quad * 8;
            bf16x8 af[4], bfr[4];
            for (int m = 0; m < 4; ++m)
                af[m] = *(const bf16x8*)&Alds[wrow + m * 16 + lr][kc];
            for (int nf = 0; nf < 4; ++nf)
                bfr[nf] = *(const bf16x8*)&Blds[wcol + nf * 16 + lr][kc];
            for (int m = 0; m < 4; ++m)
                for (int nf = 0; nf < 4; ++nf)
                    acc[m][nf] = __builtin_amdgcn_mfma_f32_16x16x32_bf16(
                        af[m], bfr[nf], acc[m][nf], 0, 0, 0);
        }
        __syncthreads();
    }

    for (int m = 0; m < 4; ++m)
        for (int nf = 0; nf < 4; ++nf)
            for (int r = 0; r < 4; ++r) {
                const int row = wrow + m * 16 + quad * 4 + r;
                const int col = e_blk * 128 + wcol + nf * 16 + lr;
                Y[(size_t)row * ypitch + col] = f2bf(acc[m][nf][r]);
            }
}

// ---------------------------------------------------------------------------
// Kernel 2: attention, 2-unit pipelined. Block = (c,b); processes hh=0 then
// hh=1. Pair-1 K/V issued into REGISTERS right after pair-0's staging barrier
// so its HBM latency hides under pair-0 QK+softmax (drained at Ps barrier);
// LDS write deferred to after pair-0 compute. O output bounced through the
// dead Ks region -> 2x b128 stores/lane instead of 16 scalar 2B stores.
// grid 1024 = exactly 4 blocks/CU (LDS 38.5 KB), all resident.
// ---------------------------------------------------------------------------
__global__ __launch_bounds__(256) void attn_kernel(
    const short* __restrict__ wsq, const short* __restrict__ wsk,
    const short* __restrict__ wsv, short* __restrict__ wso)
{
    __shared__ __align__(16) short Ks[32][264];
    __shared__ __align__(16) short Vs[32][258];
    __shared__ __align__(16) short Ps[4][16][40];

    const int tid = threadIdx.x;
    const int pb  = blockIdx.x;              // 0..1023 = c*B + b
    const int b   = pb & (B_ - 1);
    const int c   = pb >> 7;

    const short* qb0 = wsq + ((size_t)(c * B_ + b) * NQ_) * E_;
    const short* kb0 = wsk + ((size_t)(c * B_ + b) * NK_) * E_;
    const short* vb0 = wsv + ((size_t)(c * B_ + b) * NK_) * E_;
    short*       ob0 = wso + ((size_t)(c * NQ_) * B_ + b) * E_;

    const int wv   = tid >> 6;
    const int lane = tid & 63;
    const int lr   = lane & 15;
    const int quad = lane >> 4;
    const int lcol = wv * 64;
    const int nloc = tid >> 5;               // 0..7
    const int ch   = tid & 31;               // 16B chunk in 512B slice

    auto loadKV = [&](const short* kb, const short* vb,
                      bf16x8 (&kr)[4], bf16x8 (&vr)[4]) {
        #pragma unroll
        for (int i = 0; i < 4; ++i)
            kr[i] = *(const bf16x8*)(kb + (size_t)(nloc + i * 8) * E_ + ch * 8);
        #pragma unroll
        for (int i = 0; i < 4; ++i)
            vr[i] = *(const bf16x8*)(vb + (size_t)(nloc + i * 8) * E_ + ch * 8);
    };
    auto writeKV = [&](bf16x8 (&kr)[4], bf16x8 (&vr)[4]) {
        #pragma unroll
        for (int i = 0; i < 4; ++i)
            *(bf16x8*)&Ks[nloc + i * 8][ch * 8] = kr[i];
        #pragma unroll
        for (int i = 0; i < 4; ++i)
            #pragma unroll
            for (int p = 0; p < 4; ++p)
                *(int*)&Vs[nloc + i * 8][ch * 8 + p * 2] = ((const int*)&vr[i])[p];
    };

    auto computeUnit = [&](const short* qb, short* ob) {
        // Q fragments direct from global (16 B contiguous per lane, L2-hot)
        const bf16x8 aq0 = *(const bf16x8*)(qb + (size_t)lr * E_ + lcol + quad * 8);
        const bf16x8 aq1 = *(const bf16x8*)(qb + (size_t)lr * E_ + lcol + 32 + quad * 8);

        f32x4 sacc0 = (f32x4){0.f, 0.f, 0.f, 0.f};
        f32x4 sacc1 = (f32x4){0.f, 0.f, 0.f, 0.f};
        {
            const int kc0 = lcol + quad * 8;
            sacc0 = __builtin_amdgcn_mfma_f32_16x16x32_bf16(aq0, *(const bf16x8*)&Ks[lr][kc0], sacc0, 0, 0, 0);
            sacc1 = __builtin_amdgcn_mfma_f32_16x16x32_bf16(aq0, *(const bf16x8*)&Ks[16 + lr][kc0], sacc1, 0, 0, 0);
            const int kc1 = lcol + 32 + quad * 8;
            sacc0 = __builtin_amdgcn_mfma_f32_16x16x32_bf16(aq1, *(const bf16x8*)&Ks[lr][kc1], sacc0, 0, 0, 0);
            sacc1 = __builtin_amdgcn_mfma_f32_16x16x32_bf16(aq1, *(const bf16x8*)&Ks[16 + lr][kc1], sacc1, 0, 0, 0);
        }

        float p0[4], p1[4];
        #pragma unroll
        for (int r = 0; r < 4; ++r) {
            const float v0 = sacc0[r] * 0.125f;
            const float v1 = sacc1[r] * 0.125f;
            float m = fmaxf(v0, v1);
            m = fmaxf(m, __shfl_xor(m, 1));
            m = fmaxf(m, __shfl_xor(m, 2));
            m = fmaxf(m, __shfl_xor(m, 4));
            m = fmaxf(m, __shfl_xor(m, 8));
            const float e0 = __expf(v0 - m);
            const float e1 = __expf(v1 - m);
            float s = e0 + e1;
            s += __shfl_xor(s, 1);
            s += __shfl_xor(s, 2);
            s += __shfl_xor(s, 4);
            s += __shfl_xor(s, 8);
            const float inv = 1.0f / s;
            p0[r] = e0 * inv;
            p1[r] = e1 * inv;
        }

        #pragma unroll
        for (int r = 0; r < 4; ++r) {
            Ps[wv][quad * 4 + r][lr]      = f2bf(p0[r]);
            Ps[wv][quad * 4 + r][16 + lr] = f2bf(p1[r]);
        }
        __syncthreads();   // also where pair-1 in-flight loads get drained
        const bf16x8 ap = *(const bf16x8*)&Ps[wv][lr][quad * 8];

        // Ks is dead past this barrier (all QK reads precede it) -> O bounce
        short* Osb = ((short*)Ks) + wv * 1024;   // 2 KB per wave

        #pragma unroll
        for (int t = 0; t < 4; ++t) {
            bf16x8 bvv;
            #pragma unroll
            for (int j = 0; j < 8; ++j)
                bvv[j] = Vs[quad * 8 + j][lcol + t * 16 + lr];
            f32x4 oacc = (f32x4){0.f, 0.f, 0.f, 0.f};
            oacc = __builtin_amdgcn_mfma_f32_16x16x32_bf16(ap, bvv, oacc, 0, 0, 0);
            #pragma unroll
            for (int r = 0; r < 4; ++r)
                Osb[(quad * 4 + r) * 64 + t * 16 + lr] = f2bf(oacc[r]);
        }

        // same-wave readback: lane -> (q row, 32B segment); coalesced stores
        const int q   = lane >> 2;
        const int seg = lane & 3;
        const bf16x8 oA = *(const bf16x8*)&Osb[q * 64 + seg * 16];
        const bf16x8 oB = *(const bf16x8*)&Osb[q * 64 + seg * 16 + 8];
        short* dst = ob + (size_t)q * (B_ * E_) + lcol + seg * 16;
        *(bf16x8*)dst       = oA;
        *(bf16x8*)(dst + 8) = oB;
    };

    // ---- pair pipeline ----
    bf16x8 kr0[4], vr0[4], kr1[4], vr1[4];
    loadKV(kb0, vb0, kr0, vr0);
    writeKV(kr0, vr0);
    __syncthreads();

    loadKV(kb0 + 256, vb0 + 256, kr1, vr1);   // hh=1 slice, in flight
    computeUnit(qb0, ob0);                     // hh=0
    __syncthreads();                           // all Vs/Ps/Osb reads done

    writeKV(kr1, vr1);
    __syncthreads();
    computeUnit(qb0 + 256, ob0 + 256);         // hh=1
}

// ---------------------------------------------------------------------------
// Kernel 3: output projection, single-stage full-K. 1024 blocks =
// (c,q) x B-quarter x O-half. Stage X(32x512) + W^T(32x512) bf16 into 64 KB
// LDS in ONE load burst (strided W gather performs the transpose), one
// barrier, 16 uninterrupted MFMAs. Barriers/block: 16 -> 1.
// 16B-chunk XOR swizzle (g ^= row&7) instead of padding.
// ---------------------------------------------------------------------------
__global__ __launch_bounds__(256) void out_proj_kernel(
    const short* __restrict__ wso, const float* __restrict__ Wp,
    float* __restrict__ out)
{
    __shared__ __align__(16) short Xlds[32 * 512];
    __shared__ __align__(16) short Wlds[32 * 512];

    const int tid = threadIdx.x;
    const int blk = blockIdx.x;
    const int cq  = blk >> 3;            // 0..127
    const int bh  = (blk >> 1) & 3;      // B quarter (32 rows)
    const int oh  = blk & 1;             // O half (32 cols)

    const short* Xb = wso + (size_t)cq * B_ * E_ + (size_t)bh * 32 * E_;
    const float* Wb = Wp  + (size_t)cq * E_ * O_ + oh * 32;
    float*       Ob = out + (size_t)cq * B_ * O_ + (size_t)bh * 32 * O_ + oh * 32;

    const int xrow = tid >> 3;           // 0..31
    const int xch  = tid & 7;            // 16B chunk sub-index
    const int o    = tid & 31;           // W column
    const int kg   = tid >> 5;           // 0..7 k-group

    // ---- issue ALL global loads up front (one latency exposure) ----------
    bf16x8 xv[8];
    #pragma unroll
    for (int s = 0; s < 8; ++s)
        xv[s] = *(const bf16x8*)(Xb + (size_t)xrow * E_ + s * 64 + xch * 8);

    float wr[8][8];
    #pragma unroll
    for (int s = 0; s < 8; ++s)
        #pragma unroll
        for (int j = 0; j < 8; ++j)
            wr[s][j] = Wb[(size_t)(s * 64 + kg * 8 + j) * O_ + o];

    // ---- convert + swizzled LDS writes -----------------------------------
    #pragma unroll
    for (int s = 0; s < 8; ++s) {
        const int g = (s * 8 + xch) ^ (xrow & 7);
        *(bf16x8*)&Xlds[xrow * 512 + g * 8] = xv[s];
    }
    #pragma unroll
    for (int s = 0; s < 8; ++s) {
        bf16x8 w8;
        #pragma unroll
        for (int j = 0; j < 8; ++j) w8[j] = f2bf(wr[s][j]);
        const int g = (s * 8 + kg) ^ (o & 7);
        *(bf16x8*)&Wlds[o * 512 + g * 8] = w8;
    }
    __syncthreads();   // the ONLY barrier

    // ---- 16 MFMA steps, K=512 --------------------------------------------
    const int wv   = tid >> 6;
    const int lane = tid & 63;
    const int lr   = lane & 15;
    const int quad = lane >> 4;
    const int rowh = wv >> 1;
    const int ohh  = wv & 1;
    const int arow = rowh * 16 + lr;
    const int brow = ohh * 16 + lr;

    f32x4 acc = (f32x4){0.f, 0.f, 0.f, 0.f};
    #pragma unroll
    for (int st = 0; st < 16; ++st) {
        const int ga = (st * 4 + quad) ^ (arow & 7);
        const int gb = (st * 4 + quad) ^ (brow & 7);
        const bf16x8 af  = *(const bf16x8*)&Xlds[arow * 512 + ga * 8];
        const bf16x8 bfr = *(const bf16x8*)&Wlds[brow * 512 + gb * 8];
        acc = __builtin_amdgcn_mfma_f32_16x16x32_bf16(af, bfr, acc, 0, 0, 0);
    }

    #pragma unroll
    for (int r = 0; r < 4; ++r)
        Ob[(size_t)(rowh * 16 + quad * 4 + r) * O_ + ohh * 16 + lr] = acc[r];
}

extern "C" void kernel_launch(void* const* d_in, const int* in_sizes, int n_in,
                              void* d_out, int out_size, void* d_ws, size_t ws_size,
                              hipStream_t stream) {
    const float* q  = (const float*)d_in[0];
    const float* k  = (const float*)d_in[1];
    const float* Wq = (const float*)d_in[2];
    const float* Wk = (const float*)d_in[3];
    const float* Wv = (const float*)d_in[4];
    const float* Wp = (const float*)d_in[5];
    float* out = (float*)d_out;

    const size_t sz_q = (size_t)C_ * NQ_ * B_ * E_;
    const size_t sz_k = (size_t)C_ * NK_ * B_ * E_;
    short* wsq = (short*)d_ws;
    short* wsk = wsq + sz_q;
    short* wsv = wsk + sz_k;
    short* wso = wsv + sz_k;

    qkv_proj_kernel<<<dim3(2560), dim3(256), 0, stream>>>(q, k, Wq, Wk, Wv, wsq, wsk, wsv);
    attn_kernel<<<dim3(1024), dim3(256), 0, stream>>>(wsq, wsk, wsv, wso);
    out_proj_kernel<<<dim3(1024), dim3(256), 0, stream>>>(wso, Wp, out);
}